// Round 12
// baseline (384.617 us; speedup 1.0000x reference)
//
#include <hip/hip_runtime.h>
#include <stdint.h>

#define B_ 8
#define S_ 1024
#define IN_DIM 512
#define DM 1024
#define H_ 16
#define DEP 64

typedef __bf16 bf16;
typedef __attribute__((ext_vector_type(8))) __bf16 bf16x8;
typedef __attribute__((ext_vector_type(4))) __bf16 bf16x4;
typedef __attribute__((ext_vector_type(4))) float f32x4;

// ---------------------------------------------------------------- async copy
static __device__ __forceinline__ void gld_lds16(const void* g, void* l) {
    __builtin_amdgcn_global_load_lds(
        (const __attribute__((address_space(1))) uint32_t*)g,
        (__attribute__((address_space(3))) uint32_t*)l, 16, 0, 0);
}

static __device__ __forceinline__ float ldin(const void* p, size_t i, int isb) {
    return isb ? (float)((const bf16*)p)[i] : ((const float*)p)[i];
}

// v13: counted-vmcnt wait + barrier, fused in ONE asm (memory clobber both sides).
// r10-verified: -10 us on the GEMMs vs __syncthreads' vmcnt(0) drain.
template<int N>
static __device__ __forceinline__ void wait_barrier() {
    if constexpr (N == 4)      asm volatile("s_waitcnt vmcnt(4) lgkmcnt(0)\ns_barrier" ::: "memory");
    else if constexpr (N == 3) asm volatile("s_waitcnt vmcnt(3) lgkmcnt(0)\ns_barrier" ::: "memory");
    else                       asm volatile("s_waitcnt vmcnt(0) lgkmcnt(0)\ns_barrier" ::: "memory");
}

// GEMM LDS tile layout (v12, kept): pair-interleaved + XOR-swizzled 16B chunks.
static __device__ __forceinline__ int ldsch(int r, int q4) {
    const int pr = r >> 1;
    return pr*8 + ((((r & 1) << 2) + q4) ^ (pr & 7));
}

// ---------------------------------------------------------------- fused prep (r8, verified)
// layout: [0,1024) maskpack | [1024,5120) xconv | [5120,8192) transpose | [8192,8198) small
__global__ __launch_bounds__(256) void prep_kernel(
    const uint16_t* __restrict__ xraw, const void* __restrict__ x,
    const void* __restrict__ wq, const void* __restrict__ wk, const void* __restrict__ wv,
    const void* __restrict__ res, const void* __restrict__ dense,
    const int* __restrict__ mask,
    bf16* __restrict__ wqT, bf16* __restrict__ wkT, bf16* __restrict__ wvT,
    bf16* __restrict__ resT, bf16* __restrict__ denseT,
    const void* b0, const void* b1, const void* b2, const void* b3,
    const void* b4, const void* b5, bf16* __restrict__ small,
    bf16* __restrict__ xc, unsigned long long* __restrict__ mb, int* __restrict__ flag)
{
    __shared__ int s_isb;
    __shared__ bf16 tile[32][33];
    const int tid = threadIdx.x;

    if (tid < 64) {
        int sane = 0;
        #pragma unroll
        for (int j = 0; j < 8; j++) {
            const uint16_t u = xraw[tid * 8 + j];
            const int e = (u >> 7) & 0xff;
            sane += ((u & 0x7fff) == 0 || (e >= 100 && e <= 140)) ? 1 : 0;
        }
        #pragma unroll
        for (int m = 1; m < 64; m <<= 1) sane += __shfl_xor(sane, m);
        if (tid == 0) s_isb = (sane >= 450) ? 1 : 0;
    }
    __syncthreads();
    const int isb = s_isb;
    const int bid = blockIdx.x;
    if (bid == 0 && tid == 0) *flag = isb;

    if (bid < 1024) {
        const int w = tid >> 6, lane = tid & 63;
        const int gw = bid * 4 + w;
        for (int c = gw; c < 262144; c += 4096) {
            const int v = mask[(size_t)c * 64 + lane];
            const unsigned long long bits = __ballot(v != 0);
            if (lane == 0) mb[c] = bits;
        }
    } else if (bid < 5120) {
        const size_t i = ((size_t)(bid - 1024) * 256 + tid) * 4;
        if (isb) {
            *(bf16x4*)(xc + i) = *(const bf16x4*)((const bf16*)x + i);
        } else {
            const float4 v = *(const float4*)((const float*)x + i);
            bf16x4 o; o[0] = (bf16)v.x; o[1] = (bf16)v.y; o[2] = (bf16)v.z; o[3] = (bf16)v.w;
            *(bf16x4*)(xc + i) = o;
        }
    } else if (bid < 8192) {
        const int t = bid - 5120;
        const int z = t >> 9, rem = t & 511;
        const void* src; bf16* dst; int kb, kd;
        if (z == 0)      { src = wq;    dst = wqT;    kb = 0;   kd = 512;  }
        else if (z == 1) { src = wk;    dst = wkT;    kb = 0;   kd = 512;  }
        else if (z == 2) { src = wv;    dst = wvT;    kb = 0;   kd = 512;  }
        else if (z == 3) { src = res;   dst = resT;   kb = 0;   kd = 512;  }
        else if (z == 4) { src = dense; dst = denseT; kb = 0;   kd = 1024; }
        else             { src = dense; dst = denseT; kb = 512; kd = 1024; }
        const int n0 = (rem & 31) * 32, k0 = (rem >> 5) * 32;
        const int tx = tid & 31, ty = tid >> 5;
        #pragma unroll
        for (int r = 0; r < 4; r++)
            tile[ty + r*8][tx] = (bf16)ldin(src, (size_t)(kb + k0 + ty + r*8) * DM + n0 + tx, isb);
        __syncthreads();
        #pragma unroll
        for (int r = 0; r < 4; r++)
            dst[(size_t)(n0 + ty + r*8) * kd + kb + k0 + tx] = tile[tx][ty + r*8];
    } else {
        const int s6 = bid - 8192;
        const void* srcs[6] = {b0, b1, b2, b3, b4, b5};
        const void* s = srcs[s6];
        for (int i = tid; i < 1024; i += 256)
            small[s6 * 1024 + i] = (bf16)ldin(s, i, isb);
    }
}

// ---------------------------------------------------------------- GEMM core 128x128 (v13, r10-verified)
template<int KDIM>
static __device__ __forceinline__ void gemm_core(
    const bf16* __restrict__ A, const bf16* __restrict__ BT,
    int m0, int n0, bf16* Asm, bf16* Bsm, f32x4 acc[4][4])
{
    const int tid = threadIdx.x, l = tid & 63, w = tid >> 6;
    const int wm = w >> 1, wn = w & 1, quad = l >> 4, l15 = l & 15;
    #pragma unroll
    for (int i = 0; i < 4; i++)
        #pragma unroll
        for (int j = 0; j < 4; j++) acc[i][j] = f32x4{0.f, 0.f, 0.f, 0.f};

    constexpr int NIT = KDIM / 32;
    const int lp  = l >> 3;
    const int s0  = (l & 7) ^ lp;
    const int rof = s0 >> 2;
    const int kch = (s0 & 3) * 8;

    auto stage = [&](int t, int bo) {
        const int k0 = t * 32;
        #pragma unroll
        for (int qq = 0; qq < 2; qq++) {
            const int row = (qq*32 + w*8 + lp)*2 + rof;
            gld_lds16(A  + (size_t)(m0 + row)*KDIM + k0 + kch, Asm + bo + (qq*256 + w*64)*8);
            gld_lds16(BT + (size_t)(n0 + row)*KDIM + k0 + kch, Bsm + bo + (qq*256 + w*64)*8);
        }
    };

    stage(0, 0);
    stage(1, 4096);
    int cur = 0;
    for (int it = 0; it < NIT; ++it) {
        if (it < NIT - 1) wait_barrier<4>();
        else              wait_barrier<0>();
        if (it + 2 < NIT)
            stage(it + 2, (cur >= 4096) ? cur - 4096 : cur + 8192);
        bf16x8 af[4], bfv[4];
        #pragma unroll
        for (int i = 0; i < 4; i++)
            af[i] = *(const bf16x8*)(Asm + cur + ldsch(wm*64 + i*16 + l15, quad)*8);
        #pragma unroll
        for (int j = 0; j < 4; j++)
            bfv[j] = *(const bf16x8*)(Bsm + cur + ldsch(wn*64 + j*16 + l15, quad)*8);
        #pragma unroll
        for (int i = 0; i < 4; i++)
            #pragma unroll
            for (int j = 0; j < 4; j++)
                acc[i][j] = __builtin_amdgcn_mfma_f32_16x16x32_bf16(af[i], bfv[j], acc[i][j], 0, 0, 0);
        cur = (cur == 8192) ? 0 : cur + 4096;
    }
}

// ---------------------------------------------------------------- QKV + residual projection
// grid (64, 32). sel: 0=Q (scaled 0.125*log2(e)), 1=K, 2=V (transposed, k-permuted), 3=residual.
#define EPI_P 132
__global__ __launch_bounds__(256) void proj_kernel(
    const bf16* __restrict__ x,
    const bf16* __restrict__ wqT, const bf16* __restrict__ wkT,
    const bf16* __restrict__ wvT, const bf16* __restrict__ resT,
    const bf16* __restrict__ small,
    bf16* __restrict__ Q, bf16* __restrict__ K, bf16* __restrict__ VtG, bf16* __restrict__ R)
{
    __shared__ alignas(16) char smem[49152];   // 3-buf staging | V-epilogue aliases
    bf16* Asm = (bf16*)smem;
    bf16* Bsm = (bf16*)(smem + 24576);
    bf16* epi = (bf16*)smem;                   // [64 cols][EPI_P] rows-pitch

    const int m0 = blockIdx.x * 128;
    const int ng = blockIdx.y * 128;
    const int sel = ng >> 10, n0 = ng & 1023;
    const bf16* BT; const bf16* bias = nullptr;
    if (sel == 0)      { BT = wqT; bias = small;        }
    else if (sel == 1) { BT = wkT; bias = small + 1024; }
    else if (sel == 2) { BT = wvT; bias = small + 2048; }
    else               { BT = resT; }

    f32x4 acc[4][4];
    gemm_core<IN_DIM>(x, BT, m0, n0, Asm, Bsm, acc);

    const int tid = threadIdx.x, l = tid & 63, w = tid >> 6;
    const int wm = w >> 1, wn = w & 1, quad = l >> 4, l15 = l & 15;

    if (sel == 2) {
        // V: stage [col][row] in LDS, emit transposed VtG[(b*16+h)*64 + d][s'] coalesced.
        // s' is k-PERMUTED within each 32-block (p = quad*8 + h2*4 + r for
        // kl = h2*16 + quad*4 + r): attn fetches both h2 fragments with ONE 16B read.
        const int bb = m0 >> 10, srow0 = m0 & 1023;
        #pragma unroll
        for (int hf = 0; hf < 2; hf++) {
            __syncthreads();
            if (wn == hf) {
                #pragma unroll
                for (int j = 0; j < 4; j++) {
                    const int cl = j*16 + l15;
                    const float bv = (float)bias[n0 + hf*64 + cl];
                    #pragma unroll
                    for (int i = 0; i < 4; i++) {
                        const int rho = wm*64 + i*16 + quad*4;
                        #pragma unroll
                        for (int r = 0; r < 4; r++)
                            epi[cl*EPI_P + rho + r] = (bf16)(acc[i][j][r] + bv);
                    }
                }
            }
            __syncthreads();
            const int hh = (n0 >> 6) + hf;
            const int sc = tid & 15;
            #pragma unroll
            for (int pass = 0; pass < 4; pass++) {
                const int dl = (tid >> 4) + pass*16;
                bf16x8 v;
                #pragma unroll
                for (int k = 0; k < 8; k++) {
                    const int pl = (sc & 3)*8 + k;                                  // pos in 32-block
                    const int kl = ((pl & 4) << 2) | ((pl & 24) >> 1) | (pl & 3);   // source pos
                    v[k] = epi[dl*EPI_P + (sc >> 2)*32 + kl];
                }
                *(bf16x8*)(VtG + ((size_t)(bb*16 + hh)*64 + dl)*S_ + srow0 + sc*8) = v;
            }
        }
        return;
    }

    #pragma unroll
    for (int j = 0; j < 4; j++) {
        const int col = n0 + wn*64 + j*16 + l15;
        const float bv = (sel < 3) ? (float)bias[col] : 0.f;
        #pragma unroll
        for (int i = 0; i < 4; i++) {
            const int rb = m0 + wm*64 + i*16 + quad*4;
            #pragma unroll
            for (int r = 0; r < 4; r++) {
                const float v = acc[i][j][r] + bv;
                // 0.125 * log2(e): scores in base-2 domain -> attn uses raw v_exp_f32.
                if (sel == 0)      Q[(size_t)(rb + r)*DM + col] = (bf16)(v * 0.18033688f);
                else if (sel == 1) K[(size_t)(rb + r)*DM + col] = (bf16)v;
                else               R[(size_t)(rb + r)*DM + col] = (bf16)v;
            }
        }
    }
}

// ---------------------------------------------------------------- flash attention v15: ZERO LDS, ZERO barriers
// r8-r11 pattern: attn invariant (~80-82 us) under throughput changes (mask prefetch
// null, -42% matrix instrs -> -1.4us) => latency/lockstep-bound: 4 waves convoy
// through __syncthreads' vmcnt(0) drain of L2/L3-latency staging loads, x16 iters.
// v15 removes the sync entirely (guide common-mistake #7 / m169: staged data that
// L2-fits is pure overhead at S=1024). K-tile (8KB) + V-tile (8KB) fit the 32KB L1,
// so the 4 waves' re-reads are L1 hits - L1 is the free LDS. Direct addresses are
// exactly what stage+unswizzle composed to (data-path identical):
//   kf[h2][c]: K[(it*64+sub*32+h2*16+l15)*DM + h*64 + (quad + 4c)*8]
//   va8[dt]  : VtG[(bh*64+dt*16+l15)*S_ + it*64 + (sub*4+quad)*8]   (k-perm baked in)
// Waves fully independent -> compiler software-pipelines; latency hidden by overlap.
// grid (8, 128): block = 128 q-rows of one (b,h); wave = 32 q-rows (2 groups of 16).
__global__ __launch_bounds__(256) void attn_kernel(
    const bf16* __restrict__ Q, const bf16* __restrict__ K, const bf16* __restrict__ VtG,
    const unsigned long long* __restrict__ mb, bf16* __restrict__ AO)
{
    const int tid = threadIdx.x, l = tid & 63, w = tid >> 6;
    const int quad = l >> 4, l15 = l & 15;

    // XCD swizzle: each XCD owns 16 complete (b,h) groups incl. all 8 q-tiles
    // -> K/V head-tiles stay L2-resident per XCD (r1-verified, FETCH 140->33MB).
    const int fid = blockIdx.y * 8 + blockIdx.x;
    const int xcd = fid & 7, idx = fid >> 3;
    const int bh  = xcd * 16 + (idx >> 3);
    const int qt  = idx & 7;
    const int b = bh >> 4, h = bh & 15;
    const int wrow = qt*128 + w*32;
    const size_t rowbase = (size_t)b * S_;

    bf16x8 qa[2][2];
    #pragma unroll
    for (int g = 0; g < 2; g++) {
        const bf16* qp = Q + (rowbase + wrow + g*16 + l15)*DM + h*DEP + quad*8;
        qa[g][0] = *(const bf16x8*)qp;
        qa[g][1] = *(const bf16x8*)(qp + 32);
    }
    const bf16* kgbase = K + rowbase*DM + h*DEP;
    const bf16* vgbase = VtG + (size_t)(b*16 + h)*64*S_;
    const unsigned long long* mbase[2];
    #pragma unroll
    for (int g = 0; g < 2; g++)
        mbase[g] = mb + ((size_t)h*S_ + wrow + g*16 + l15) * 16;   // u64 per 64-k tile, q = l15

    uint32_t bmr[4];
    #pragma unroll
    for (int r = 0; r < 4; r++) bmr[r] = 1u << (quad*4 + r);

    bf16x8 onesv8;
    #pragma unroll
    for (int r = 0; r < 8; r++) onesv8[r] = (bf16)1.0f;

    f32x4 oT[2][4];           // O^T: [d = dt*16 + quad*4 + r][q = l15]
    f32x4 lacc[2];            // ones-row mfma accumulator
    #pragma unroll
    for (int g = 0; g < 2; g++) {
        lacc[g] = f32x4{0.f,0.f,0.f,0.f};
        #pragma unroll
        for (int dt = 0; dt < 4; dt++) oT[g][dt] = f32x4{0.f,0.f,0.f,0.f};
    }

    uint32_t mlo[2], mhi[2];
    #pragma unroll
    for (int g = 0; g < 2; g++) {
        const unsigned long long mw = mbase[g][0];
        mlo[g] = (uint32_t)mw; mhi[g] = (uint32_t)(mw >> 32);
    }

    for (int it = 0; it < 16; it++) {
        const uint32_t cmlo[2] = {mlo[0], mlo[1]}, cmhi[2] = {mhi[0], mhi[1]};
        if (it + 1 < 16) {
            #pragma unroll
            for (int g = 0; g < 2; g++) {
                const unsigned long long mw = mbase[g][it + 1];
                mlo[g] = (uint32_t)mw; mhi[g] = (uint32_t)(mw >> 32);
            }
        }
        const int kr0 = it * 64;

        #pragma unroll
        for (int sub = 0; sub < 2; sub++) {
            bf16x8 kf[2][2];
            bf16x8 va8[4];
            #pragma unroll
            for (int h2 = 0; h2 < 2; h2++) {
                const bf16* kp = kgbase + (size_t)(kr0 + sub*32 + h2*16 + l15)*DM + quad*8;
                kf[h2][0] = *(const bf16x8*)kp;
                kf[h2][1] = *(const bf16x8*)(kp + 32);
            }
            #pragma unroll
            for (int dt = 0; dt < 4; dt++)
                va8[dt] = *(const bf16x8*)(vgbase + (size_t)(dt*16 + l15)*S_ + kr0 + (sub*4 + quad)*8);

            #pragma unroll
            for (int g = 0; g < 2; g++) {
                f32x4 st[2];
                __builtin_amdgcn_s_setprio(1);
                #pragma unroll
                for (int h2 = 0; h2 < 2; h2++) {
                    f32x4 z = {0.f,0.f,0.f,0.f};
                    z = __builtin_amdgcn_mfma_f32_16x16x32_bf16(kf[h2][0], qa[g][0], z, 0, 0, 0);
                    z = __builtin_amdgcn_mfma_f32_16x16x32_bf16(kf[h2][1], qa[g][1], z, 0, 0, 0);
                    st[h2] = z;
                }
                __builtin_amdgcn_s_setprio(0);
                const uint32_t msk = sub ? cmhi[g] : cmlo[g];
                // pb8 packed in va8's k-order pi: j<4 <- h2=0 (bits 0-15), j>=4 <- h2=1 (bits 16-31)
                bf16x8 pb8;
                #pragma unroll
                for (int r = 0; r < 4; r++) {
                    const float e0 = __builtin_amdgcn_exp2f(st[0][r]);   // scale pre-folded into Q
                    pb8[r]     = (bf16)((msk & bmr[r]) ? e0 : 0.f);
                    const float e1 = __builtin_amdgcn_exp2f(st[1][r]);
                    pb8[4 + r] = (bf16)(((msk >> 16) & bmr[r]) ? e1 : 0.f);
                }
                __builtin_amdgcn_s_setprio(1);
                lacc[g] = __builtin_amdgcn_mfma_f32_16x16x32_bf16(onesv8, pb8, lacc[g], 0, 0, 0);
                #pragma unroll
                for (int dt = 0; dt < 4; dt++)
                    oT[g][dt] = __builtin_amdgcn_mfma_f32_16x16x32_bf16(va8[dt], pb8, oT[g][dt], 0, 0, 0);
                __builtin_amdgcn_s_setprio(0);
            }
        }
    }

    #pragma unroll
    for (int g = 0; g < 2; g++) {
        const float inv = 1.0f / lacc[g][0];
        bf16* aor = AO + (rowbase + wrow + g*16 + l15)*DM + h*DEP;
        #pragma unroll
        for (int dt = 0; dt < 4; dt++) {
            bf16x4 ov;
            #pragma unroll
            for (int r = 0; r < 4; r++) ov[r] = (bf16)(oT[g][dt][r] * inv);
            *(bf16x4*)(aor + dt*16 + quad*4) = ov;
        }
    }
}

// ---------------------------------------------------------------- dense + residual (in-place R)
// 64x128 tile, grid (128,8). v13 counted-vmcnt pipeline (3 bufs, 36 KB), r10-verified.
__global__ __launch_bounds__(256) void dense_kernel(
    const bf16* __restrict__ AOin, const bf16* __restrict__ dT,
    const bf16* __restrict__ db, bf16* __restrict__ R)
{
    __shared__ alignas(16) bf16 Asm[3*64*32];    // 3 x 4 KB
    __shared__ alignas(16) bf16 Bsm[3*128*32];   // 3 x 8 KB
    const int m0 = blockIdx.x * 64, n0 = blockIdx.y * 128;
    const int tid = threadIdx.x, l = tid & 63, w = tid >> 6;
    const int wm = w >> 1, wn = w & 1, quad = l >> 4, l15 = l & 15;

    f32x4 acc[2][4];
    #pragma unroll
    for (int i = 0; i < 2; i++)
        #pragma unroll
        for (int j = 0; j < 4; j++) acc[i][j] = f32x4{0.f, 0.f, 0.f, 0.f};

    const int lp  = l >> 3;
    const int s0  = (l & 7) ^ lp;
    const int rof = s0 >> 2;
    const int kch = (s0 & 3) * 8;

    auto stage = [&](int t, int boA, int boB) {
        const int k1 = t * 32;
        gld_lds16(AOin + (size_t)(m0 + (w*8 + lp)*2 + rof)*DM + k1 + kch, Asm + boA + (w*64)*8);
        #pragma unroll
        for (int qq = 0; qq < 2; qq++) {
            const int row = (qq*32 + w*8 + lp)*2 + rof;
            gld_lds16(dT + (size_t)(n0 + row)*DM + k1 + kch, Bsm + boB + (qq*256 + w*64)*8);
        }
    };

    stage(0, 0, 0);
    stage(1, 2048, 4096);
    int curA = 0, curB = 0;
    for (int it = 0; it < 32; ++it) {
        if (it < 31) wait_barrier<3>();
        else         wait_barrier<0>();
        if (it + 2 < 32)
            stage(it + 2, (curA >= 2048) ? curA - 2048 : curA + 4096,
                          (curB >= 4096) ? curB - 4096 : curB + 8192);
        bf16x8 af[2], bfv[4];
        #pragma unroll
        for (int i = 0; i < 2; i++)
            af[i] = *(const bf16x8*)(Asm + curA + ldsch(wm*32 + i*16 + l15, quad)*8);
        #pragma unroll
        for (int j = 0; j < 4; j++)
            bfv[j] = *(const bf16x8*)(Bsm + curB + ldsch(wn*64 + j*16 + l15, quad)*8);
        #pragma unroll
        for (int i = 0; i < 2; i++)
            #pragma unroll
            for (int j = 0; j < 4; j++)
                acc[i][j] = __builtin_amdgcn_mfma_f32_16x16x32_bf16(af[i], bfv[j], acc[i][j], 0, 0, 0);
        curA = (curA == 4096) ? 0 : curA + 2048;
        curB = (curB == 8192) ? 0 : curB + 4096;
    }

    #pragma unroll
    for (int j = 0; j < 4; j++) {
        const int col = n0 + wn*64 + j*16 + l15;
        const float bv = (float)db[col];
        #pragma unroll
        for (int i = 0; i < 2; i++) {
            const int rb = m0 + wm*32 + i*16 + quad*4;
            #pragma unroll
            for (int r = 0; r < 4; r++) {
                const size_t idx = (size_t)(rb + r)*DM + col;
                R[idx] = (bf16)((float)R[idx] + acc[i][j][r] + bv);
            }
        }
    }
}

// ---------------------------------------------------------------- LayerNorm (wave-per-row, r8 verified)
__global__ __launch_bounds__(256) void ln_kernel(
    const bf16* __restrict__ R, const bf16* __restrict__ small,
    void* __restrict__ out, const int* __restrict__ flag)
{
    const int isb = *flag;
    const int row  = blockIdx.x * 4 + (threadIdx.x >> 6);
    const int lane = threadIdx.x & 63;
    const bf16* rp = R + (size_t)row*DM;

    float v[16];
    float s = 0.f;
    #pragma unroll
    for (int k = 0; k < 4; k++) {
        const bf16x4 rv = *(const bf16x4*)(rp + k*256 + lane*4);
        #pragma unroll
        for (int r = 0; r < 4; r++) { v[k*4+r] = (float)rv[r]; s += v[k*4+r]; }
    }
    #pragma unroll
    for (int m = 1; m < 64; m <<= 1) s += __shfl_xor(s, m);
    const float mu = s * (1.0f/DM);

    float q = 0.f;
    #pragma unroll
    for (int i = 0; i < 16; i++) { v[i] -= mu; q += v[i]*v[i]; }
    #pragma unroll
    for (int m = 1; m < 64; m <<= 1) q += __shfl_xor(q, m);
    const float rstd = rsqrtf(q * (1.0f/DM) + 1e-5f);

    #pragma unroll
    for (int k = 0; k < 4; k++) {
        const int col = k*256 + lane*4;
        const bf16x4 gv = *(const bf16x4*)(small + 4*1024 + col);
        const bf16x4 bv = *(const bf16x4*)(small + 5*1024 + col);
        float o[4];
        #pragma unroll
        for (int r = 0; r < 4; r++) o[r] = v[k*4+r]*rstd*(float)gv[r] + (float)bv[r];
        if (isb) {
            bf16x4 ov;
            #pragma unroll
            for (int r = 0; r < 4; r++) ov[r] = (bf16)o[r];
            *(bf16x4*)((bf16*)out + (size_t)row*DM + col) = ov;
        } else {
            float4 ov = {o[0], o[1], o[2], o[3]};
            *(float4*)((float*)out + (size_t)row*DM + col) = ov;
        }
    }
}

// ---------------------------------------------------------------- launch
extern "C" void kernel_launch(void* const* d_in, const int* in_sizes, int n_in,
                              void* d_out, int out_size, void* d_ws, size_t ws_size,
                              hipStream_t stream) {
    const int* mask = (const int*)d_in[1];

    char* ws = (char*)d_ws;
    bf16* wqT   = (bf16*)(ws);
    bf16* wkT   = (bf16*)(ws + ((size_t)1 << 20));
    bf16* wvT   = (bf16*)(ws + ((size_t)2 << 20));
    bf16* resT  = (bf16*)(ws + ((size_t)3 << 20));
    bf16* dT    = (bf16*)(ws + ((size_t)4 << 20));   // 2 MB
    bf16* small = (bf16*)(ws + ((size_t)6 << 20));   // 12 KB
    int*  flag  = (int*) (ws + ((size_t)6 << 20) + 16384);
    unsigned long long* mbits = (unsigned long long*)(ws + ((size_t)7 << 20)); // 2 MB
    bf16* Qb    = (bf16*)(ws + ((size_t)9  << 20));  // 16 MB (also AO)
    bf16* Kb    = (bf16*)(ws + ((size_t)25 << 20));  // 16 MB
    bf16* VtG   = (bf16*)(ws + ((size_t)41 << 20));  // 16 MB, V transposed [bh][d][s-perm]
    bf16* R     = (bf16*)(ws + ((size_t)57 << 20));  // 16 MB; total 73 MB
    bf16* xc    = (bf16*)d_out;                      // dead until ln_kernel

    prep_kernel<<<8198, 256, 0, stream>>>(
        (const uint16_t*)d_in[0], d_in[0],
        d_in[2], d_in[4], d_in[6], d_in[10], d_in[8],
        mask,
        wqT, wkT, wvT, resT, dT,
        d_in[3], d_in[5], d_in[7], d_in[9], d_in[11], d_in[12], small,
        xc, mbits, flag);
    proj_kernel<<<dim3(64, 32), 256, 0, stream>>>(
        xc, wqT, wkT, wvT, resT, small, Qb, Kb, VtG, R);
    attn_kernel<<<dim3(8, 128), 256, 0, stream>>>(Qb, Kb, VtG, mbits, Qb /*AO aliases Q*/);
    dense_kernel<<<dim3(128, 8), 256, 0, stream>>>(Qb, dT, small + 3*1024, R);
    ln_kernel<<<2048, 256, 0, stream>>>(R, small, d_out, flag);
}

// Round 13
// 320.163 us; speedup vs baseline: 1.2013x; 1.2013x over previous
//
#include <hip/hip_runtime.h>
#include <stdint.h>

#define B_ 8
#define S_ 1024
#define IN_DIM 512
#define DM 1024
#define H_ 16
#define DEP 64

typedef __bf16 bf16;
typedef __attribute__((ext_vector_type(8))) __bf16 bf16x8;
typedef __attribute__((ext_vector_type(4))) __bf16 bf16x4;
typedef __attribute__((ext_vector_type(4))) float f32x4;

// ---------------------------------------------------------------- async copy
static __device__ __forceinline__ void gld_lds16(const void* g, void* l) {
    __builtin_amdgcn_global_load_lds(
        (const __attribute__((address_space(1))) uint32_t*)g,
        (__attribute__((address_space(3))) uint32_t*)l, 16, 0, 0);
}

static __device__ __forceinline__ float ldin(const void* p, size_t i, int isb) {
    return isb ? (float)((const bf16*)p)[i] : ((const float*)p)[i];
}

// counted-vmcnt wait + barrier, fused in ONE asm (memory clobber both sides).
// r10-verified on the GEMMs (-10 us vs vmcnt(0) drain).
template<int N>
static __device__ __forceinline__ void wait_barrier() {
    if constexpr (N == 6)      asm volatile("s_waitcnt vmcnt(6) lgkmcnt(0)\ns_barrier" ::: "memory");
    else if constexpr (N == 4) asm volatile("s_waitcnt vmcnt(4) lgkmcnt(0)\ns_barrier" ::: "memory");
    else if constexpr (N == 3) asm volatile("s_waitcnt vmcnt(3) lgkmcnt(0)\ns_barrier" ::: "memory");
    else if constexpr (N == 2) asm volatile("s_waitcnt vmcnt(2) lgkmcnt(0)\ns_barrier" ::: "memory");
    else                       asm volatile("s_waitcnt vmcnt(0) lgkmcnt(0)\ns_barrier" ::: "memory");
}
// compiler-only fence: pins VMEM issue order across prologue groups, emits nothing.
#define CFENCE() asm volatile("" ::: "memory")

// GEMM LDS tile layout (v12, kept): pair-interleaved + XOR-swizzled 16B chunks.
static __device__ __forceinline__ int ldsch(int r, int q4) {
    const int pr = r >> 1;
    return pr*8 + ((((r & 1) << 2) + q4) ^ (pr & 7));
}

// ---------------------------------------------------------------- fused prep (r8, verified)
// layout: [0,1024) maskpack | [1024,5120) xconv | [5120,8192) transpose | [8192,8198) small
__global__ __launch_bounds__(256) void prep_kernel(
    const uint16_t* __restrict__ xraw, const void* __restrict__ x,
    const void* __restrict__ wq, const void* __restrict__ wk, const void* __restrict__ wv,
    const void* __restrict__ res, const void* __restrict__ dense,
    const int* __restrict__ mask,
    bf16* __restrict__ wqT, bf16* __restrict__ wkT, bf16* __restrict__ wvT,
    bf16* __restrict__ resT, bf16* __restrict__ denseT,
    const void* b0, const void* b1, const void* b2, const void* b3,
    const void* b4, const void* b5, bf16* __restrict__ small,
    bf16* __restrict__ xc, unsigned long long* __restrict__ mb, int* __restrict__ flag)
{
    __shared__ int s_isb;
    __shared__ bf16 tile[32][33];
    const int tid = threadIdx.x;

    if (tid < 64) {
        int sane = 0;
        #pragma unroll
        for (int j = 0; j < 8; j++) {
            const uint16_t u = xraw[tid * 8 + j];
            const int e = (u >> 7) & 0xff;
            sane += ((u & 0x7fff) == 0 || (e >= 100 && e <= 140)) ? 1 : 0;
        }
        #pragma unroll
        for (int m = 1; m < 64; m <<= 1) sane += __shfl_xor(sane, m);
        if (tid == 0) s_isb = (sane >= 450) ? 1 : 0;
    }
    __syncthreads();
    const int isb = s_isb;
    const int bid = blockIdx.x;
    if (bid == 0 && tid == 0) *flag = isb;

    if (bid < 1024) {
        const int w = tid >> 6, lane = tid & 63;
        const int gw = bid * 4 + w;
        for (int c = gw; c < 262144; c += 4096) {
            const int v = mask[(size_t)c * 64 + lane];
            const unsigned long long bits = __ballot(v != 0);
            if (lane == 0) mb[c] = bits;
        }
    } else if (bid < 5120) {
        const size_t i = ((size_t)(bid - 1024) * 256 + tid) * 4;
        if (isb) {
            *(bf16x4*)(xc + i) = *(const bf16x4*)((const bf16*)x + i);
        } else {
            const float4 v = *(const float4*)((const float*)x + i);
            bf16x4 o; o[0] = (bf16)v.x; o[1] = (bf16)v.y; o[2] = (bf16)v.z; o[3] = (bf16)v.w;
            *(bf16x4*)(xc + i) = o;
        }
    } else if (bid < 8192) {
        const int t = bid - 5120;
        const int z = t >> 9, rem = t & 511;
        const void* src; bf16* dst; int kb, kd;
        if (z == 0)      { src = wq;    dst = wqT;    kb = 0;   kd = 512;  }
        else if (z == 1) { src = wk;    dst = wkT;    kb = 0;   kd = 512;  }
        else if (z == 2) { src = wv;    dst = wvT;    kb = 0;   kd = 512;  }
        else if (z == 3) { src = res;   dst = resT;   kb = 0;   kd = 512;  }
        else if (z == 4) { src = dense; dst = denseT; kb = 0;   kd = 1024; }
        else             { src = dense; dst = denseT; kb = 512; kd = 1024; }
        const int n0 = (rem & 31) * 32, k0 = (rem >> 5) * 32;
        const int tx = tid & 31, ty = tid >> 5;
        #pragma unroll
        for (int r = 0; r < 4; r++)
            tile[ty + r*8][tx] = (bf16)ldin(src, (size_t)(kb + k0 + ty + r*8) * DM + n0 + tx, isb);
        __syncthreads();
        #pragma unroll
        for (int r = 0; r < 4; r++)
            dst[(size_t)(n0 + ty + r*8) * kd + kb + k0 + tx] = tile[tx][ty + r*8];
    } else {
        const int s6 = bid - 8192;
        const void* srcs[6] = {b0, b1, b2, b3, b4, b5};
        const void* s = srcs[s6];
        for (int i = tid; i < 1024; i += 256)
            small[s6 * 1024 + i] = (bf16)ldin(s, i, isb);
    }
}

// ---------------------------------------------------------------- GEMM core 128x128 (v13, r10-verified)
template<int KDIM>
static __device__ __forceinline__ void gemm_core(
    const bf16* __restrict__ A, const bf16* __restrict__ BT,
    int m0, int n0, bf16* Asm, bf16* Bsm, f32x4 acc[4][4])
{
    const int tid = threadIdx.x, l = tid & 63, w = tid >> 6;
    const int wm = w >> 1, wn = w & 1, quad = l >> 4, l15 = l & 15;
    #pragma unroll
    for (int i = 0; i < 4; i++)
        #pragma unroll
        for (int j = 0; j < 4; j++) acc[i][j] = f32x4{0.f, 0.f, 0.f, 0.f};

    constexpr int NIT = KDIM / 32;
    const int lp  = l >> 3;
    const int s0  = (l & 7) ^ lp;
    const int rof = s0 >> 2;
    const int kch = (s0 & 3) * 8;

    auto stage = [&](int t, int bo) {
        const int k0 = t * 32;
        #pragma unroll
        for (int qq = 0; qq < 2; qq++) {
            const int row = (qq*32 + w*8 + lp)*2 + rof;
            gld_lds16(A  + (size_t)(m0 + row)*KDIM + k0 + kch, Asm + bo + (qq*256 + w*64)*8);
            gld_lds16(BT + (size_t)(n0 + row)*KDIM + k0 + kch, Bsm + bo + (qq*256 + w*64)*8);
        }
    };

    stage(0, 0);
    stage(1, 4096);
    int cur = 0;
    for (int it = 0; it < NIT; ++it) {
        if (it < NIT - 1) wait_barrier<4>();
        else              wait_barrier<0>();
        if (it + 2 < NIT)
            stage(it + 2, (cur >= 4096) ? cur - 4096 : cur + 8192);
        bf16x8 af[4], bfv[4];
        #pragma unroll
        for (int i = 0; i < 4; i++)
            af[i] = *(const bf16x8*)(Asm + cur + ldsch(wm*64 + i*16 + l15, quad)*8);
        #pragma unroll
        for (int j = 0; j < 4; j++)
            bfv[j] = *(const bf16x8*)(Bsm + cur + ldsch(wn*64 + j*16 + l15, quad)*8);
        #pragma unroll
        for (int i = 0; i < 4; i++)
            #pragma unroll
            for (int j = 0; j < 4; j++)
                acc[i][j] = __builtin_amdgcn_mfma_f32_16x16x32_bf16(af[i], bfv[j], acc[i][j], 0, 0, 0);
        cur = (cur == 8192) ? 0 : cur + 4096;
    }
}

// ---------------------------------------------------------------- QKV + residual projection
// grid (64, 32). sel: 0=Q (scaled 0.125*log2(e)), 1=K, 2=V (transposed, k-permuted), 3=residual.
#define EPI_P 132
__global__ __launch_bounds__(256) void proj_kernel(
    const bf16* __restrict__ x,
    const bf16* __restrict__ wqT, const bf16* __restrict__ wkT,
    const bf16* __restrict__ wvT, const bf16* __restrict__ resT,
    const bf16* __restrict__ small,
    bf16* __restrict__ Q, bf16* __restrict__ K, bf16* __restrict__ VtG, bf16* __restrict__ R)
{
    __shared__ alignas(16) char smem[49152];   // 3-buf staging | V-epilogue aliases
    bf16* Asm = (bf16*)smem;
    bf16* Bsm = (bf16*)(smem + 24576);
    bf16* epi = (bf16*)smem;                   // [64 cols][EPI_P] rows-pitch

    const int m0 = blockIdx.x * 128;
    const int ng = blockIdx.y * 128;
    const int sel = ng >> 10, n0 = ng & 1023;
    const bf16* BT; const bf16* bias = nullptr;
    if (sel == 0)      { BT = wqT; bias = small;        }
    else if (sel == 1) { BT = wkT; bias = small + 1024; }
    else if (sel == 2) { BT = wvT; bias = small + 2048; }
    else               { BT = resT; }

    f32x4 acc[4][4];
    gemm_core<IN_DIM>(x, BT, m0, n0, Asm, Bsm, acc);

    const int tid = threadIdx.x, l = tid & 63, w = tid >> 6;
    const int wm = w >> 1, wn = w & 1, quad = l >> 4, l15 = l & 15;

    if (sel == 2) {
        // V: stage [col][row] in LDS, emit transposed VtG[(b*16+h)*64 + d][s'] coalesced.
        // s' is k-PERMUTED within each 32-block (p = quad*8 + h2*4 + r for
        // kl = h2*16 + quad*4 + r): attn fetches both h2 fragments with ONE 16B read.
        const int bb = m0 >> 10, srow0 = m0 & 1023;
        #pragma unroll
        for (int hf = 0; hf < 2; hf++) {
            __syncthreads();
            if (wn == hf) {
                #pragma unroll
                for (int j = 0; j < 4; j++) {
                    const int cl = j*16 + l15;
                    const float bv = (float)bias[n0 + hf*64 + cl];
                    #pragma unroll
                    for (int i = 0; i < 4; i++) {
                        const int rho = wm*64 + i*16 + quad*4;
                        #pragma unroll
                        for (int r = 0; r < 4; r++)
                            epi[cl*EPI_P + rho + r] = (bf16)(acc[i][j][r] + bv);
                    }
                }
            }
            __syncthreads();
            const int hh = (n0 >> 6) + hf;
            const int sc = tid & 15;
            #pragma unroll
            for (int pass = 0; pass < 4; pass++) {
                const int dl = (tid >> 4) + pass*16;
                bf16x8 v;
                #pragma unroll
                for (int k = 0; k < 8; k++) {
                    const int pl = (sc & 3)*8 + k;                                  // pos in 32-block
                    const int kl = ((pl & 4) << 2) | ((pl & 24) >> 1) | (pl & 3);   // source pos
                    v[k] = epi[dl*EPI_P + (sc >> 2)*32 + kl];
                }
                *(bf16x8*)(VtG + ((size_t)(bb*16 + hh)*64 + dl)*S_ + srow0 + sc*8) = v;
            }
        }
        return;
    }

    #pragma unroll
    for (int j = 0; j < 4; j++) {
        const int col = n0 + wn*64 + j*16 + l15;
        const float bv = (sel < 3) ? (float)bias[col] : 0.f;
        #pragma unroll
        for (int i = 0; i < 4; i++) {
            const int rb = m0 + wm*64 + i*16 + quad*4;
            #pragma unroll
            for (int r = 0; r < 4; r++) {
                const float v = acc[i][j][r] + bv;
                // 0.125 * log2(e): scores in base-2 domain -> attn uses raw v_exp_f32.
                if (sel == 0)      Q[(size_t)(rb + r)*DM + col] = (bf16)(v * 0.18033688f);
                else if (sel == 1) K[(size_t)(rb + r)*DM + col] = (bf16)v;
                else               R[(size_t)(rb + r)*DM + col] = (bf16)v;
            }
        }
    }
}

// ---------------------------------------------------------------- flash attention v16
// v15 (no-LDS) REFUTED: direct strided reads (2KB/lane stride) are uncoalesced ->
// 143 us. LDS staging is the coalescer, not overhead. v16 = r11's verified v14
// compute + the r10-proven counted-vmcnt pipeline: 3 K/V buffers, depth-2 prefetch,
// wait_barrier<6> instead of __syncthreads' vmcnt(0) drain (the convoy diagnosed
// r11). Steady-state in-flight at the wait = it-1 region's 6 VMEM ops (4 gld_lds +
// 2 mask loads); region counts are intra-order-independent (asm clobbers fence all
// VMEM region-to-region); prologue order pinned by CFENCE. Tail: it-1 region = 2
// mask loads -> wait<2>. Buffer (it+2)%3 overwrite is safe: read during it-1,
// published by this barrier.
// grid (8, 128): block = 128 q-rows of one (b,h); wave = 32 q-rows (2 groups of 16).
__global__ __launch_bounds__(256) void attn_kernel(
    const bf16* __restrict__ Q, const bf16* __restrict__ K, const bf16* __restrict__ VtG,
    const unsigned long long* __restrict__ mb, bf16* __restrict__ AO)
{
    __shared__ alignas(16) bf16 Ksm[3*64*64];   // 3 x 8KB, [krow][d], 16B-chunk XOR-swizzled
    __shared__ alignas(16) bf16 Vsm[3*64*64];   // 3 x 8KB, [d][k-permuted], same swizzle

    const int tid = threadIdx.x, l = tid & 63, w = tid >> 6;
    const int quad = l >> 4, l15 = l & 15;

    // XCD swizzle: each XCD owns 16 complete (b,h) groups incl. all 8 q-tiles.
    const int fid = blockIdx.y * 8 + blockIdx.x;
    const int xcd = fid & 7, idx = fid >> 3;
    const int bh  = xcd * 16 + (idx >> 3);
    const int qt  = idx & 7;
    const int b = bh >> 4, h = bh & 15;
    const int wrow = qt*128 + w*32;
    const size_t rowbase = (size_t)b * S_;

    bf16x8 qa[2][2];
    #pragma unroll
    for (int g = 0; g < 2; g++) {
        const bf16* qp = Q + (rowbase + wrow + g*16 + l15)*DM + h*DEP + quad*8;
        qa[g][0] = *(const bf16x8*)qp;
        qa[g][1] = *(const bf16x8*)(qp + 32);
    }
    const bf16* kgbase = K + rowbase*DM + h*DEP;
    const bf16* vgbase = VtG + (size_t)(b*16 + h)*64*S_;
    const unsigned long long* mbase[2];
    #pragma unroll
    for (int g = 0; g < 2; g++)
        mbase[g] = mb + ((size_t)h*S_ + wrow + g*16 + l15) * 16;   // u64 per 64-k tile, q = l15

    uint32_t bmr[4];
    #pragma unroll
    for (int r = 0; r < 4; r++) bmr[r] = 1u << (quad*4 + r);

    bf16x8 onesv8;
    #pragma unroll
    for (int r = 0; r < 8; r++) onesv8[r] = (bf16)1.0f;

    f32x4 oT[2][4];           // O^T: [d = dt*16 + quad*4 + r][q = l15]
    f32x4 lacc[2];            // ones-row mfma accumulator
    #pragma unroll
    for (int g = 0; g < 2; g++) {
        lacc[g] = f32x4{0.f,0.f,0.f,0.f};
        #pragma unroll
        for (int dt = 0; dt < 4; dt++) oT[g][dt] = f32x4{0.f,0.f,0.f,0.f};
    }

    const int srow8 = l >> 3;
    const int gch   = (l & 7) ^ srow8;   // pre-swizzled source chunk

    // stage tile t into buffer at element offset bo (4 gld_lds per thread)
    auto stage = [&](int t, int bo) {
        const int kt = t * 64;
        #pragma unroll
        for (int q = 0; q < 2; q++) {
            const int row = q*32 + w*8 + srow8;
            gld_lds16(kgbase + (size_t)(kt + row)*DM + gch*8, Ksm + bo + (q*256 + w*64)*8);
            gld_lds16(vgbase + (size_t)row*S_ + kt + gch*8,   Vsm + bo + (q*256 + w*64)*8);
        }
    };

    // prologue: order pinned oldest-first by compiler fences
    stage(0, 0);
    CFENCE();
    stage(1, 4096);
    CFENCE();
    uint32_t mlo[2], mhi[2];
    #pragma unroll
    for (int g = 0; g < 2; g++) {
        const unsigned long long mw = mbase[g][0];
        mlo[g] = (uint32_t)mw; mhi[g] = (uint32_t)(mw >> 32);
    }

    const int rsw = l15 & 7;   // read-side swizzle key

    int cur = 0;
    for (int it = 0; it < 16; it++) {
        // publishes tile it; leaves it-1-region's newer loads in flight
        if (it < 15) wait_barrier<6>();
        else         wait_barrier<2>();
        const bf16* Kc = Ksm + cur;
        const bf16* Vc = Vsm + cur;

        const uint32_t cmlo[2] = {mlo[0], mlo[1]}, cmhi[2] = {mhi[0], mhi[1]};
        if (it + 1 < 16) {
            #pragma unroll
            for (int g = 0; g < 2; g++) {
                const unsigned long long mw = mbase[g][it + 1];
                mlo[g] = (uint32_t)mw; mhi[g] = (uint32_t)(mw >> 32);
            }
        }
        if (it + 2 < 16)
            stage(it + 2, (cur >= 4096) ? cur - 4096 : cur + 8192);

        #pragma unroll
        for (int sub = 0; sub < 2; sub++) {
            bf16x8 kf[2][2];
            bf16x8 va8[4];
            #pragma unroll
            for (int h2 = 0; h2 < 2; h2++) {
                const int krow = sub*32 + h2*16 + l15;
                kf[h2][0] = *(const bf16x8*)(Kc + krow*64 + ((quad    ) ^ rsw)*8);
                kf[h2][1] = *(const bf16x8*)(Kc + krow*64 + ((quad + 4) ^ rsw)*8);
            }
            #pragma unroll
            for (int dt = 0; dt < 4; dt++)
                va8[dt] = *(const bf16x8*)(Vc + (dt*16 + l15)*64 + ((sub*4 + quad) ^ rsw)*8);

            #pragma unroll
            for (int g = 0; g < 2; g++) {
                f32x4 st[2];
                __builtin_amdgcn_s_setprio(1);
                #pragma unroll
                for (int h2 = 0; h2 < 2; h2++) {
                    f32x4 z = {0.f,0.f,0.f,0.f};
                    z = __builtin_amdgcn_mfma_f32_16x16x32_bf16(kf[h2][0], qa[g][0], z, 0, 0, 0);
                    z = __builtin_amdgcn_mfma_f32_16x16x32_bf16(kf[h2][1], qa[g][1], z, 0, 0, 0);
                    st[h2] = z;
                }
                __builtin_amdgcn_s_setprio(0);
                const uint32_t msk = sub ? cmhi[g] : cmlo[g];
                // pb8 packed in va8's k-order pi: j<4 <- h2=0 (bits 0-15), j>=4 <- h2=1 (bits 16-31)
                bf16x8 pb8;
                #pragma unroll
                for (int r = 0; r < 4; r++) {
                    const float e0 = __builtin_amdgcn_exp2f(st[0][r]);   // scale pre-folded into Q
                    pb8[r]     = (bf16)((msk & bmr[r]) ? e0 : 0.f);
                    const float e1 = __builtin_amdgcn_exp2f(st[1][r]);
                    pb8[4 + r] = (bf16)(((msk >> 16) & bmr[r]) ? e1 : 0.f);
                }
                __builtin_amdgcn_s_setprio(1);
                lacc[g] = __builtin_amdgcn_mfma_f32_16x16x32_bf16(onesv8, pb8, lacc[g], 0, 0, 0);
                #pragma unroll
                for (int dt = 0; dt < 4; dt++)
                    oT[g][dt] = __builtin_amdgcn_mfma_f32_16x16x32_bf16(va8[dt], pb8, oT[g][dt], 0, 0, 0);
                __builtin_amdgcn_s_setprio(0);
            }
        }
        cur = (cur == 8192) ? 0 : cur + 4096;
    }

    #pragma unroll
    for (int g = 0; g < 2; g++) {
        const float inv = 1.0f / lacc[g][0];
        bf16* aor = AO + (rowbase + wrow + g*16 + l15)*DM + h*DEP;
        #pragma unroll
        for (int dt = 0; dt < 4; dt++) {
            bf16x4 ov;
            #pragma unroll
            for (int r = 0; r < 4; r++) ov[r] = (bf16)(oT[g][dt][r] * inv);
            *(bf16x4*)(aor + dt*16 + quad*4) = ov;
        }
    }
}

// ---------------------------------------------------------------- dense + residual (in-place R)
// 64x128 tile, grid (128,8). v13 counted-vmcnt pipeline (3 bufs, 36 KB), r10-verified.
__global__ __launch_bounds__(256) void dense_kernel(
    const bf16* __restrict__ AOin, const bf16* __restrict__ dT,
    const bf16* __restrict__ db, bf16* __restrict__ R)
{
    __shared__ alignas(16) bf16 Asm[3*64*32];    // 3 x 4 KB
    __shared__ alignas(16) bf16 Bsm[3*128*32];   // 3 x 8 KB
    const int m0 = blockIdx.x * 64, n0 = blockIdx.y * 128;
    const int tid = threadIdx.x, l = tid & 63, w = tid >> 6;
    const int wm = w >> 1, wn = w & 1, quad = l >> 4, l15 = l & 15;

    f32x4 acc[2][4];
    #pragma unroll
    for (int i = 0; i < 2; i++)
        #pragma unroll
        for (int j = 0; j < 4; j++) acc[i][j] = f32x4{0.f, 0.f, 0.f, 0.f};

    const int lp  = l >> 3;
    const int s0  = (l & 7) ^ lp;
    const int rof = s0 >> 2;
    const int kch = (s0 & 3) * 8;

    auto stage = [&](int t, int boA, int boB) {
        const int k1 = t * 32;
        gld_lds16(AOin + (size_t)(m0 + (w*8 + lp)*2 + rof)*DM + k1 + kch, Asm + boA + (w*64)*8);
        #pragma unroll
        for (int qq = 0; qq < 2; qq++) {
            const int row = (qq*32 + w*8 + lp)*2 + rof;
            gld_lds16(dT + (size_t)(n0 + row)*DM + k1 + kch, Bsm + boB + (qq*256 + w*64)*8);
        }
    };

    stage(0, 0, 0);
    stage(1, 2048, 4096);
    int curA = 0, curB = 0;
    for (int it = 0; it < 32; ++it) {
        if (it < 31) wait_barrier<3>();
        else         wait_barrier<0>();
        if (it + 2 < 32)
            stage(it + 2, (curA >= 2048) ? curA - 2048 : curA + 4096,
                          (curB >= 4096) ? curB - 4096 : curB + 8192);
        bf16x8 af[2], bfv[4];
        #pragma unroll
        for (int i = 0; i < 2; i++)
            af[i] = *(const bf16x8*)(Asm + curA + ldsch(wm*32 + i*16 + l15, quad)*8);
        #pragma unroll
        for (int j = 0; j < 4; j++)
            bfv[j] = *(const bf16x8*)(Bsm + curB + ldsch(wn*64 + j*16 + l15, quad)*8);
        #pragma unroll
        for (int i = 0; i < 2; i++)
            #pragma unroll
            for (int j = 0; j < 4; j++)
                acc[i][j] = __builtin_amdgcn_mfma_f32_16x16x32_bf16(af[i], bfv[j], acc[i][j], 0, 0, 0);
        curA = (curA == 4096) ? 0 : curA + 2048;
        curB = (curB == 8192) ? 0 : curB + 4096;
    }

    #pragma unroll
    for (int j = 0; j < 4; j++) {
        const int col = n0 + wn*64 + j*16 + l15;
        const float bv = (float)db[col];
        #pragma unroll
        for (int i = 0; i < 2; i++) {
            const int rb = m0 + wm*32 + i*16 + quad*4;
            #pragma unroll
            for (int r = 0; r < 4; r++) {
                const size_t idx = (size_t)(rb + r)*DM + col;
                R[idx] = (bf16)((float)R[idx] + acc[i][j][r] + bv);
            }
        }
    }
}

// ---------------------------------------------------------------- LayerNorm (wave-per-row, r8 verified)
__global__ __launch_bounds__(256) void ln_kernel(
    const bf16* __restrict__ R, const bf16* __restrict__ small,
    void* __restrict__ out, const int* __restrict__ flag)
{
    const int isb = *flag;
    const int row  = blockIdx.x * 4 + (threadIdx.x >> 6);
    const int lane = threadIdx.x & 63;
    const bf16* rp = R + (size_t)row*DM;

    float v[16];
    float s = 0.f;
    #pragma unroll
    for (int k = 0; k < 4; k++) {
        const bf16x4 rv = *(const bf16x4*)(rp + k*256 + lane*4);
        #pragma unroll
        for (int r = 0; r < 4; r++) { v[k*4+r] = (float)rv[r]; s += v[k*4+r]; }
    }
    #pragma unroll
    for (int m = 1; m < 64; m <<= 1) s += __shfl_xor(s, m);
    const float mu = s * (1.0f/DM);

    float q = 0.f;
    #pragma unroll
    for (int i = 0; i < 16; i++) { v[i] -= mu; q += v[i]*v[i]; }
    #pragma unroll
    for (int m = 1; m < 64; m <<= 1) q += __shfl_xor(q, m);
    const float rstd = rsqrtf(q * (1.0f/DM) + 1e-5f);

    #pragma unroll
    for (int k = 0; k < 4; k++) {
        const int col = k*256 + lane*4;
        const bf16x4 gv = *(const bf16x4*)(small + 4*1024 + col);
        const bf16x4 bv = *(const bf16x4*)(small + 5*1024 + col);
        float o[4];
        #pragma unroll
        for (int r = 0; r < 4; r++) o[r] = v[k*4+r]*rstd*(float)gv[r] + (float)bv[r];
        if (isb) {
            bf16x4 ov;
            #pragma unroll
            for (int r = 0; r < 4; r++) ov[r] = (bf16)o[r];
            *(bf16x4*)((bf16*)out + (size_t)row*DM + col) = ov;
        } else {
            float4 ov = {o[0], o[1], o[2], o[3]};
            *(float4*)((float*)out + (size_t)row*DM + col) = ov;
        }
    }
}

// ---------------------------------------------------------------- launch
extern "C" void kernel_launch(void* const* d_in, const int* in_sizes, int n_in,
                              void* d_out, int out_size, void* d_ws, size_t ws_size,
                              hipStream_t stream) {
    const int* mask = (const int*)d_in[1];

    char* ws = (char*)d_ws;
    bf16* wqT   = (bf16*)(ws);
    bf16* wkT   = (bf16*)(ws + ((size_t)1 << 20));
    bf16* wvT   = (bf16*)(ws + ((size_t)2 << 20));
    bf16* resT  = (bf16*)(ws + ((size_t)3 << 20));
    bf16* dT    = (bf16*)(ws + ((size_t)4 << 20));   // 2 MB
    bf16* small = (bf16*)(ws + ((size_t)6 << 20));   // 12 KB
    int*  flag  = (int*) (ws + ((size_t)6 << 20) + 16384);
    unsigned long long* mbits = (unsigned long long*)(ws + ((size_t)7 << 20)); // 2 MB
    bf16* Qb    = (bf16*)(ws + ((size_t)9  << 20));  // 16 MB (also AO)
    bf16* Kb    = (bf16*)(ws + ((size_t)25 << 20));  // 16 MB
    bf16* VtG   = (bf16*)(ws + ((size_t)41 << 20));  // 16 MB, V transposed [bh][d][s-perm]
    bf16* R     = (bf16*)(ws + ((size_t)57 << 20));  // 16 MB; total 73 MB
    bf16* xc    = (bf16*)d_out;                      // dead until ln_kernel

    prep_kernel<<<8198, 256, 0, stream>>>(
        (const uint16_t*)d_in[0], d_in[0],
        d_in[2], d_in[4], d_in[6], d_in[10], d_in[8],
        mask,
        wqT, wkT, wvT, resT, dT,
        d_in[3], d_in[5], d_in[7], d_in[9], d_in[11], d_in[12], small,
        xc, mbits, flag);
    proj_kernel<<<dim3(64, 32), 256, 0, stream>>>(
        xc, wqT, wkT, wvT, resT, small, Qb, Kb, VtG, R);
    attn_kernel<<<dim3(8, 128), 256, 0, stream>>>(Qb, Kb, VtG, mbits, Qb /*AO aliases Q*/);
    dense_kernel<<<dim3(128, 8), 256, 0, stream>>>(Qb, dT, small + 3*1024, R);
    ln_kernel<<<2048, 256, 0, stream>>>(R, small, d_out, flag);
}